// Round 12
// baseline (272.797 us; speedup 1.0000x reference)
//
#include <hip/hip_runtime.h>
#include <math.h>

#define NSITE 100
#define NOCC  50
#define DIM   128
#define KDET  4
#define NTAB  400                         // K*(N_UP+N_DOWN)

// ---------------------------------------------------------------------------
// R18: GEMM collapsed into T[4][400]/P'[144][400] table adds.
// R23: two-panel LU (25 live cols max): clean alloc, 181us @ VALUBusy 86%.
// R24/25: phase-2 broadcasts -> ds_bpermute (LDS pipe): 141.7us. Works:
//      independent per-column chains hide crossbar latency.
// R26/R27: bpermute within ~1 step of the serial pivot chain: hard regress.
// R28: occupancy 60->72%: flat. det is cross-lane-ISSUE bound.
// R29: combine fused into det, tp split-K: total FLAT (195us) -> the ~54us
//      non-det residue is fixed overhead; only det (141us) is compressible.
// R30 (this round): BLOCKED PANELS (w=5) in phases 1/3. Factor 5 cols
//      serially (readlane pivot chain + within-panel updates, mult/pivot
//      kept in regs), then REPLAY the 5 steps onto trailing cols via
//      ds_bpermute -- step-outer, next-panel-cols first (in-order LDS
//      completion => serial restart waits only on oldest ops). Gives
//      phases 1/3 the phase-2 ILP structure: 600 readlane updates -> 100,
//      +500 bpermutes on the near-idle DS pipe. Bit-identical op sequence.
// ---------------------------------------------------------------------------

// Wave64 max-reduction via DPP (VALU-only). Lane 63 ends with global max.
__device__ __forceinline__ unsigned dpp_max64_to_lane63(unsigned x) {
  unsigned t;
  t = (unsigned)__builtin_amdgcn_update_dpp((int)x, (int)x, 0x111, 0xf, 0xf, false);
  x = x > t ? x : t;
  t = (unsigned)__builtin_amdgcn_update_dpp((int)x, (int)x, 0x112, 0xf, 0xf, false);
  x = x > t ? x : t;
  t = (unsigned)__builtin_amdgcn_update_dpp((int)x, (int)x, 0x114, 0xf, 0xf, false);
  x = x > t ? x : t;
  t = (unsigned)__builtin_amdgcn_update_dpp((int)x, (int)x, 0x118, 0xf, 0xf, false);
  x = x > t ? x : t;
  t = (unsigned)__builtin_amdgcn_update_dpp((int)x, (int)x, 0x142, 0xa, 0xf, false);
  x = x > t ? x : t;
  t = (unsigned)__builtin_amdgcn_update_dpp((int)x, (int)x, 0x143, 0xc, 0xf, false);
  x = x > t ? x : t;
  return x;
}

// 25-wide repeat
#define REPC(X) X(0) X(1) X(2) X(3) X(4) X(5) X(6) X(7) X(8) X(9) \
  X(10) X(11) X(12) X(13) X(14) X(15) X(16) X(17) X(18) X(19) \
  X(20) X(21) X(22) X(23) X(24)

// ---- Precompute: T[c][j] = tok[c].W_j ; P'[s][j] = pos[s].W_j + b_j ------
// Split-K x4: lanes (4q+h) handle quarter h of output q; shfl_xor combine.
__global__ __launch_bounds__(256) void tp_kernel(
    const float* __restrict__ tok, const float* __restrict__ pos,
    const float* __restrict__ W,   const float* __restrict__ bvec,
    float* __restrict__ T, float* __restrict__ P)
{
  const int gid = blockIdx.x * 256 + threadIdx.x;
  if (gid >= 148 * NTAB * 4) return;
  const int q   = gid >> 2;
  const int h   = gid & 3;
  const int row = q / NTAB;
  const int col = q - row * NTAB;
  const float4* h4 = (const float4*)((row < 4) ? (tok + (size_t)row * DIM)
                                               : (pos + (size_t)(row - 4) * DIM));
  const float4* w4 = (const float4*)(W + (size_t)col * DIM);
  float acc = 0.0f;
  #pragma unroll
  for (int i = 0; i < 8; ++i) {
    float4 a = h4[h * 8 + i], b = w4[h * 8 + i];
    acc = fmaf(a.x, b.x, acc);
    acc = fmaf(a.y, b.y, acc);
    acc = fmaf(a.z, b.z, acc);
    acc = fmaf(a.w, b.w, acc);
  }
  acc += __shfl_xor(acc, 1);
  acc += __shfl_xor(acc, 2);
  if (h == 0) {
    if (row < 4) T[(size_t)row * NTAB + col] = acc;
    else         P[(size_t)(row - 4) * NTAB + col] = acc + bvec[col];
  }
}

// One block per batch. 8 waves: wave w -> spin = w>>2, det k = w&3.
// Lane r owns row r of phi. Two-panel LU per wave; combine fused at end.
__global__ __launch_bounds__(512)
__attribute__((amdgpu_waves_per_eu(8)))
void det_kernel(
    const int*   __restrict__ configs,   // (B,100) int32
    const float* __restrict__ T,         // (4,400)
    const float* __restrict__ P,         // (144,400)  includes bias
    float*       __restrict__ out,       // planar complex64
    int B)
{
  const int b = blockIdx.x;

  __shared__ float stash[8][25][50];       // 40000B multiplier stash
  __shared__ int cfg[NSITE];               // 400B
  __shared__ int idxs[2][NOCC];            // 400B
  __shared__ unsigned long long omask[2][2];  // 32B
  __shared__ double detl[2][KDET][2];      // 128B  -> total 40960B exactly

  const int tid = threadIdx.x;

  // ---- wave-parallel occupied-index build for BOTH spins ----
  int  cval = 0;
  bool ou = false, od = false;
  if (tid < NSITE) {
    cval = configs[(size_t)b * NSITE + tid];
    cfg[tid] = cval;
    ou = (cval == 1) || (cval == 3);
    od = (cval == 2) || (cval == 3);
  }
  const unsigned long long balu = __ballot(ou);
  const unsigned long long bald = __ballot(od);
  if ((tid & 63) == 0 && tid < 128) {
    omask[0][tid >> 6] = balu;
    omask[1][tid >> 6] = bald;
  }
  __syncthreads();
  if (tid < NSITE) {
    #pragma unroll
    for (int s = 0; s < 2; ++s) {
      const unsigned long long m0 = omask[s][0], m1 = omask[s][1];
      const bool occv = (s == 0) ? ou : od;
      const int mtot = __popcll(m0) + __popcll(m1);
      const int need = (mtot < NOCC) ? (NOCC - mtot) : 0;
      int pocc;
      if (tid >= 64) pocc = __popcll(m0) + __popcll(m1 & ((1ull << (tid - 64)) - 1ull));
      else           pocc = __popcll(m0 & ((1ull << tid) - 1ull));
      const int punocc = tid - pocc;
      const bool sel = occv ? (pocc < NOCC) : (punocc < need);
      const int  poscap = (pocc  < NOCC) ? pocc  : NOCC;
      const int  pfill  = (punocc < need) ? punocc : need;
      if (sel) idxs[s][poscap + pfill] = tid;
    }
  }
  __syncthreads();

  const int lane   = tid & 63;
  const int wave   = tid >> 6;
  const int wave_u = __builtin_amdgcn_readfirstlane(wave);
  const int spin   = wave_u >> 2;
  const int kd     = wave_u & 3;
  const int colbase = spin * 200 + kd * 50;              // uniform

  const bool act  = (lane < NOCC);
  const int  site = idxs[spin][act ? lane : 0];
  const int  cc0  = cfg[site];
  const float* Trow = T + (size_t)cc0  * NTAB + colbase;
  const float* Prow = P + (size_t)site * NTAB + colbase;
  // colbase multiple of 50 -> byte offset multiple of 200 -> 8-aligned
  const float2* T2 = (const float2*)Trow;
  const float2* P2 = (const float2*)Prow;

  // ================= phase 1: cols 0..24 in c0..c24 =================
  #define DECLC(i) float c##i;
  REPC(DECLC)
  #undef DECLC
  #define LQ(i0, i1) { float2 a = T2[(i0) / 2], d = P2[(i0) / 2]; \
      c##i0 = a.x + d.x; c##i1 = a.y + d.y; }
  LQ(0, 1)  LQ(2, 3)  LQ(4, 5)  LQ(6, 7)  LQ(8, 9)  LQ(10, 11)
  LQ(12, 13) LQ(14, 15) LQ(16, 17) LQ(18, 19) LQ(20, 21) LQ(22, 23)
  #undef LQ
  c24 = Trow[24] + Prow[24];
  #define ZC(i) c##i = act ? c##i : 0.0f;
  REPC(ZC)
  #undef ZC

  unsigned aliveq = act ? 0xFFFFFFFFu : 0u;   // per-lane alive mask
  float    mant_prod = 1.0f;                  // pivot mantissa product < 2^50
  int      esum = 0;
  unsigned sgnx = 0u;
  unsigned long long chosen = 0ull;
  int      invsum = 0;
  const unsigned lu = (unsigned)lane;
  unsigned long long pp[3] = {0ull, 0ull, 0ull};  // packed pivot lanes, 6b ea

  // serial pivot step on column CJ; records stash+pp (phase-1 only).
  // Outputs: MV (masked multiplier, VGPR), PV (pivot lane, SGPR).
  #define PSTEP(JIDX, CJ, MV, PV) { \
    unsigned key = ((__float_as_uint(CJ) & 0x7FFFFFC0u) | lu) & aliveq; \
    key = dpp_max64_to_lane63(key); \
    PV = __builtin_amdgcn_readlane((int)key, 63) & 63; \
    const unsigned pb = (unsigned)__builtin_amdgcn_readlane( \
        __float_as_int(CJ), PV); \
    esum += (int)((pb >> 23) & 0xFFu) - 127; \
    sgnx ^= (pb & 0x80000000u); \
    mant_prod *= __uint_as_float((pb & 0x007FFFFFu) | 0x3F800000u); \
    invsum += __popcll(chosen >> (PV + 1)); \
    chosen |= 1ull << (unsigned)PV; \
    aliveq = (lane == PV) ? 0u : aliveq; \
    pp[(JIDX) / 10] |= ((unsigned long long)(unsigned)PV) << (6 * ((JIDX) % 10)); \
    const float piv = __uint_as_float(pb); \
    float r0 = __builtin_amdgcn_rcpf(piv); \
    r0 = fmaf(fmaf(-piv, r0, 1.0f), r0, r0); \
    const float rp = ((pb & 0x7FFFFFFFu) != 0u) ? r0 : 0.0f; \
    MV = __uint_as_float(__float_as_uint((CJ) * rp) & aliveq); \
    if (act) stash[wave_u][(JIDX)][lane] = MV; }

  // phase-3 variant: no stash/pp
  #define PSTEP3(CJ, MV, PV) { \
    unsigned key = ((__float_as_uint(CJ) & 0x7FFFFFC0u) | lu) & aliveq; \
    key = dpp_max64_to_lane63(key); \
    PV = __builtin_amdgcn_readlane((int)key, 63) & 63; \
    const unsigned pb = (unsigned)__builtin_amdgcn_readlane( \
        __float_as_int(CJ), PV); \
    esum += (int)((pb >> 23) & 0xFFu) - 127; \
    sgnx ^= (pb & 0x80000000u); \
    mant_prod *= __uint_as_float((pb & 0x007FFFFFu) | 0x3F800000u); \
    invsum += __popcll(chosen >> (PV + 1)); \
    chosen |= 1ull << (unsigned)PV; \
    aliveq = (lane == PV) ? 0u : aliveq; \
    const float piv = __uint_as_float(pb); \
    float r0 = __builtin_amdgcn_rcpf(piv); \
    r0 = fmaf(fmaf(-piv, r0, 1.0f), r0, r0); \
    const float rp = ((pb & 0x7FFFFFFFu) != 0u) ? r0 : 0.0f; \
    MV = __uint_as_float(__float_as_uint((CJ) * rp) & aliveq); }

  // readlane update (VALU pipe -- within-panel only)
  #define RLU(CL, MV, PV) { const float pc = __int_as_float( \
      __builtin_amdgcn_readlane(__float_as_int(CL), PV)); \
      CL = fmaf(-(MV), pc, CL); }
  // bpermute update (LDS pipe -- panel replay, independent chains)
  #define BPU(CL, MV, AV) { const float pc = __int_as_float( \
      __builtin_amdgcn_ds_bpermute(AV, __float_as_int(CL))); \
      CL = fmaf(-(MV), pc, CL); }
  #define BP5(Ca,Cb,Cc,Cd,Ce,M,A) \
      BPU(Ca,M,A) BPU(Cb,M,A) BPU(Cc,M,A) BPU(Cd,M,A) BPU(Ce,M,A)

  // ---- phase 1, panel 0: cols c0..c4 (steps 0..4), trail c5..c24 ----
  {
    float m0,m1,m2,m3,m4; int q0_,q1_,q2_,q3_,q4_;
    PSTEP(0, c0, m0, q0_)
    RLU(c1,m0,q0_) RLU(c2,m0,q0_) RLU(c3,m0,q0_) RLU(c4,m0,q0_)
    PSTEP(1, c1, m1, q1_)
    RLU(c2,m1,q1_) RLU(c3,m1,q1_) RLU(c4,m1,q1_)
    PSTEP(2, c2, m2, q2_)
    RLU(c3,m2,q2_) RLU(c4,m2,q2_)
    PSTEP(3, c3, m3, q3_)
    RLU(c4,m3,q3_)
    PSTEP(4, c4, m4, q4_)
    const int a0=q0_<<2,a1=q1_<<2,a2=q2_<<2,a3=q3_<<2,a4=q4_<<2;
    BP5(c5,c6,c7,c8,c9,m0,a0) BP5(c10,c11,c12,c13,c14,m0,a0)
    BP5(c15,c16,c17,c18,c19,m0,a0) BP5(c20,c21,c22,c23,c24,m0,a0)
    __builtin_amdgcn_sched_barrier(0);
    BP5(c5,c6,c7,c8,c9,m1,a1) BP5(c10,c11,c12,c13,c14,m1,a1)
    BP5(c15,c16,c17,c18,c19,m1,a1) BP5(c20,c21,c22,c23,c24,m1,a1)
    __builtin_amdgcn_sched_barrier(0);
    BP5(c5,c6,c7,c8,c9,m2,a2) BP5(c10,c11,c12,c13,c14,m2,a2)
    BP5(c15,c16,c17,c18,c19,m2,a2) BP5(c20,c21,c22,c23,c24,m2,a2)
    __builtin_amdgcn_sched_barrier(0);
    BP5(c5,c6,c7,c8,c9,m3,a3) BP5(c10,c11,c12,c13,c14,m3,a3)
    BP5(c15,c16,c17,c18,c19,m3,a3) BP5(c20,c21,c22,c23,c24,m3,a3)
    __builtin_amdgcn_sched_barrier(0);
    BP5(c5,c6,c7,c8,c9,m4,a4) BP5(c10,c11,c12,c13,c14,m4,a4)
    BP5(c15,c16,c17,c18,c19,m4,a4) BP5(c20,c21,c22,c23,c24,m4,a4)
    __builtin_amdgcn_sched_barrier(0);
  }
  // ---- phase 1, panel 1: cols c5..c9 (steps 5..9), trail c10..c24 ----
  {
    float m0,m1,m2,m3,m4; int q0_,q1_,q2_,q3_,q4_;
    PSTEP(5, c5, m0, q0_)
    RLU(c6,m0,q0_) RLU(c7,m0,q0_) RLU(c8,m0,q0_) RLU(c9,m0,q0_)
    PSTEP(6, c6, m1, q1_)
    RLU(c7,m1,q1_) RLU(c8,m1,q1_) RLU(c9,m1,q1_)
    PSTEP(7, c7, m2, q2_)
    RLU(c8,m2,q2_) RLU(c9,m2,q2_)
    PSTEP(8, c8, m3, q3_)
    RLU(c9,m3,q3_)
    PSTEP(9, c9, m4, q4_)
    const int a0=q0_<<2,a1=q1_<<2,a2=q2_<<2,a3=q3_<<2,a4=q4_<<2;
    BP5(c10,c11,c12,c13,c14,m0,a0) BP5(c15,c16,c17,c18,c19,m0,a0)
    BP5(c20,c21,c22,c23,c24,m0,a0)
    __builtin_amdgcn_sched_barrier(0);
    BP5(c10,c11,c12,c13,c14,m1,a1) BP5(c15,c16,c17,c18,c19,m1,a1)
    BP5(c20,c21,c22,c23,c24,m1,a1)
    __builtin_amdgcn_sched_barrier(0);
    BP5(c10,c11,c12,c13,c14,m2,a2) BP5(c15,c16,c17,c18,c19,m2,a2)
    BP5(c20,c21,c22,c23,c24,m2,a2)
    __builtin_amdgcn_sched_barrier(0);
    BP5(c10,c11,c12,c13,c14,m3,a3) BP5(c15,c16,c17,c18,c19,m3,a3)
    BP5(c20,c21,c22,c23,c24,m3,a3)
    __builtin_amdgcn_sched_barrier(0);
    BP5(c10,c11,c12,c13,c14,m4,a4) BP5(c15,c16,c17,c18,c19,m4,a4)
    BP5(c20,c21,c22,c23,c24,m4,a4)
    __builtin_amdgcn_sched_barrier(0);
  }
  // ---- phase 1, panel 2: cols c10..c14 (steps 10..14), trail c15..c24 ----
  {
    float m0,m1,m2,m3,m4; int q0_,q1_,q2_,q3_,q4_;
    PSTEP(10, c10, m0, q0_)
    RLU(c11,m0,q0_) RLU(c12,m0,q0_) RLU(c13,m0,q0_) RLU(c14,m0,q0_)
    PSTEP(11, c11, m1, q1_)
    RLU(c12,m1,q1_) RLU(c13,m1,q1_) RLU(c14,m1,q1_)
    PSTEP(12, c12, m2, q2_)
    RLU(c13,m2,q2_) RLU(c14,m2,q2_)
    PSTEP(13, c13, m3, q3_)
    RLU(c14,m3,q3_)
    PSTEP(14, c14, m4, q4_)
    const int a0=q0_<<2,a1=q1_<<2,a2=q2_<<2,a3=q3_<<2,a4=q4_<<2;
    BP5(c15,c16,c17,c18,c19,m0,a0) BP5(c20,c21,c22,c23,c24,m0,a0)
    __builtin_amdgcn_sched_barrier(0);
    BP5(c15,c16,c17,c18,c19,m1,a1) BP5(c20,c21,c22,c23,c24,m1,a1)
    __builtin_amdgcn_sched_barrier(0);
    BP5(c15,c16,c17,c18,c19,m2,a2) BP5(c20,c21,c22,c23,c24,m2,a2)
    __builtin_amdgcn_sched_barrier(0);
    BP5(c15,c16,c17,c18,c19,m3,a3) BP5(c20,c21,c22,c23,c24,m3,a3)
    __builtin_amdgcn_sched_barrier(0);
    BP5(c15,c16,c17,c18,c19,m4,a4) BP5(c20,c21,c22,c23,c24,m4,a4)
    __builtin_amdgcn_sched_barrier(0);
  }
  // ---- phase 1, panel 3: cols c15..c19 (steps 15..19), trail c20..c24 ----
  {
    float m0,m1,m2,m3,m4; int q0_,q1_,q2_,q3_,q4_;
    PSTEP(15, c15, m0, q0_)
    RLU(c16,m0,q0_) RLU(c17,m0,q0_) RLU(c18,m0,q0_) RLU(c19,m0,q0_)
    PSTEP(16, c16, m1, q1_)
    RLU(c17,m1,q1_) RLU(c18,m1,q1_) RLU(c19,m1,q1_)
    PSTEP(17, c17, m2, q2_)
    RLU(c18,m2,q2_) RLU(c19,m2,q2_)
    PSTEP(18, c18, m3, q3_)
    RLU(c19,m3,q3_)
    PSTEP(19, c19, m4, q4_)
    const int a0=q0_<<2,a1=q1_<<2,a2=q2_<<2,a3=q3_<<2,a4=q4_<<2;
    BP5(c20,c21,c22,c23,c24,m0,a0)
    BP5(c20,c21,c22,c23,c24,m1,a1)
    BP5(c20,c21,c22,c23,c24,m2,a2)
    BP5(c20,c21,c22,c23,c24,m3,a3)
    BP5(c20,c21,c22,c23,c24,m4,a4)
    __builtin_amdgcn_sched_barrier(0);
  }
  // ---- phase 1, panel 4: cols c20..c24 (steps 20..24), no trail ----
  {
    float m0,m1,m2,m3,m4; int q0_,q1_,q2_,q3_,q4_;
    PSTEP(20, c20, m0, q0_)
    RLU(c21,m0,q0_) RLU(c22,m0,q0_) RLU(c23,m0,q0_) RLU(c24,m0,q0_)
    PSTEP(21, c21, m1, q1_)
    RLU(c22,m1,q1_) RLU(c23,m1,q1_) RLU(c24,m1,q1_)
    PSTEP(22, c22, m2, q2_)
    RLU(c23,m2,q2_) RLU(c24,m2,q2_)
    PSTEP(23, c23, m3, q3_)
    RLU(c24,m3,q3_)
    PSTEP(24, c24, m4, q4_)
    (void)m0;(void)m1;(void)m2;(void)m3;(void)m4;
  }

  // ================= phase 2: cols 25..49, replay steps 0..24 ============
  #define DECLT(i) float t##i;
  REPC(DECLT)
  #undef DECLT
  #define LT(i) t##i = Trow[25 + (i)] + Prow[25 + (i)];
  REPC(LT)
  #undef LT
  #define ZT(i) t##i = act ? t##i : 0.0f;
  REPC(ZT)
  #undef ZT

  #define BT(L) { const float pc = __int_as_float( \
      __builtin_amdgcn_ds_bpermute(pa, __float_as_int(t##L))); \
      t##L = fmaf(-mult, pc, t##L); }

  #define P2J(J) { \
    const int pa = ((int)((pp[(J) / 10] >> (6 * ((J) % 10))) & 63ull)) << 2; \
    const float mult = stash[wave_u][(J)][lane < NOCC ? lane : 0]; \
    BT(0)  BT(1)  BT(2)  BT(3)  BT(4)  BT(5) \
    __builtin_amdgcn_sched_barrier(0); \
    BT(6)  BT(7)  BT(8)  BT(9)  BT(10) BT(11) \
    __builtin_amdgcn_sched_barrier(0); \
    BT(12) BT(13) BT(14) BT(15) BT(16) BT(17) \
    __builtin_amdgcn_sched_barrier(0); \
    BT(18) BT(19) BT(20) BT(21) BT(22) BT(23) BT(24) \
    __builtin_amdgcn_sched_barrier(0); \
  }
  P2J(0)  P2J(1)  P2J(2)  P2J(3)  P2J(4)  P2J(5)  P2J(6)  P2J(7)
  P2J(8)  P2J(9)  P2J(10) P2J(11) P2J(12) P2J(13) P2J(14) P2J(15)
  P2J(16) P2J(17) P2J(18) P2J(19) P2J(20) P2J(21) P2J(22) P2J(23)
  P2J(24)
  #undef P2J
  #undef BT

  // ======= phase 3: factor steps 25..49 on t0..t24, blocked w=5 =========
  // ---- panel 0: t0..t4, trail t5..t24 ----
  {
    float m0,m1,m2,m3,m4; int q0_,q1_,q2_,q3_,q4_;
    PSTEP3(t0, m0, q0_)
    RLU(t1,m0,q0_) RLU(t2,m0,q0_) RLU(t3,m0,q0_) RLU(t4,m0,q0_)
    PSTEP3(t1, m1, q1_)
    RLU(t2,m1,q1_) RLU(t3,m1,q1_) RLU(t4,m1,q1_)
    PSTEP3(t2, m2, q2_)
    RLU(t3,m2,q2_) RLU(t4,m2,q2_)
    PSTEP3(t3, m3, q3_)
    RLU(t4,m3,q3_)
    PSTEP3(t4, m4, q4_)
    const int a0=q0_<<2,a1=q1_<<2,a2=q2_<<2,a3=q3_<<2,a4=q4_<<2;
    BP5(t5,t6,t7,t8,t9,m0,a0) BP5(t10,t11,t12,t13,t14,m0,a0)
    BP5(t15,t16,t17,t18,t19,m0,a0) BP5(t20,t21,t22,t23,t24,m0,a0)
    __builtin_amdgcn_sched_barrier(0);
    BP5(t5,t6,t7,t8,t9,m1,a1) BP5(t10,t11,t12,t13,t14,m1,a1)
    BP5(t15,t16,t17,t18,t19,m1,a1) BP5(t20,t21,t22,t23,t24,m1,a1)
    __builtin_amdgcn_sched_barrier(0);
    BP5(t5,t6,t7,t8,t9,m2,a2) BP5(t10,t11,t12,t13,t14,m2,a2)
    BP5(t15,t16,t17,t18,t19,m2,a2) BP5(t20,t21,t22,t23,t24,m2,a2)
    __builtin_amdgcn_sched_barrier(0);
    BP5(t5,t6,t7,t8,t9,m3,a3) BP5(t10,t11,t12,t13,t14,m3,a3)
    BP5(t15,t16,t17,t18,t19,m3,a3) BP5(t20,t21,t22,t23,t24,m3,a3)
    __builtin_amdgcn_sched_barrier(0);
    BP5(t5,t6,t7,t8,t9,m4,a4) BP5(t10,t11,t12,t13,t14,m4,a4)
    BP5(t15,t16,t17,t18,t19,m4,a4) BP5(t20,t21,t22,t23,t24,m4,a4)
    __builtin_amdgcn_sched_barrier(0);
  }
  // ---- panel 1: t5..t9, trail t10..t24 ----
  {
    float m0,m1,m2,m3,m4; int q0_,q1_,q2_,q3_,q4_;
    PSTEP3(t5, m0, q0_)
    RLU(t6,m0,q0_) RLU(t7,m0,q0_) RLU(t8,m0,q0_) RLU(t9,m0,q0_)
    PSTEP3(t6, m1, q1_)
    RLU(t7,m1,q1_) RLU(t8,m1,q1_) RLU(t9,m1,q1_)
    PSTEP3(t7, m2, q2_)
    RLU(t8,m2,q2_) RLU(t9,m2,q2_)
    PSTEP3(t8, m3, q3_)
    RLU(t9,m3,q3_)
    PSTEP3(t9, m4, q4_)
    const int a0=q0_<<2,a1=q1_<<2,a2=q2_<<2,a3=q3_<<2,a4=q4_<<2;
    BP5(t10,t11,t12,t13,t14,m0,a0) BP5(t15,t16,t17,t18,t19,m0,a0)
    BP5(t20,t21,t22,t23,t24,m0,a0)
    __builtin_amdgcn_sched_barrier(0);
    BP5(t10,t11,t12,t13,t14,m1,a1) BP5(t15,t16,t17,t18,t19,m1,a1)
    BP5(t20,t21,t22,t23,t24,m1,a1)
    __builtin_amdgcn_sched_barrier(0);
    BP5(t10,t11,t12,t13,t14,m2,a2) BP5(t15,t16,t17,t18,t19,m2,a2)
    BP5(t20,t21,t22,t23,t24,m2,a2)
    __builtin_amdgcn_sched_barrier(0);
    BP5(t10,t11,t12,t13,t14,m3,a3) BP5(t15,t16,t17,t18,t19,m3,a3)
    BP5(t20,t21,t22,t23,t24,m3,a3)
    __builtin_amdgcn_sched_barrier(0);
    BP5(t10,t11,t12,t13,t14,m4,a4) BP5(t15,t16,t17,t18,t19,m4,a4)
    BP5(t20,t21,t22,t23,t24,m4,a4)
    __builtin_amdgcn_sched_barrier(0);
  }
  // ---- panel 2: t10..t14, trail t15..t24 ----
  {
    float m0,m1,m2,m3,m4; int q0_,q1_,q2_,q3_,q4_;
    PSTEP3(t10, m0, q0_)
    RLU(t11,m0,q0_) RLU(t12,m0,q0_) RLU(t13,m0,q0_) RLU(t14,m0,q0_)
    PSTEP3(t11, m1, q1_)
    RLU(t12,m1,q1_) RLU(t13,m1,q1_) RLU(t14,m1,q1_)
    PSTEP3(t12, m2, q2_)
    RLU(t13,m2,q2_) RLU(t14,m2,q2_)
    PSTEP3(t13, m3, q3_)
    RLU(t14,m3,q3_)
    PSTEP3(t14, m4, q4_)
    const int a0=q0_<<2,a1=q1_<<2,a2=q2_<<2,a3=q3_<<2,a4=q4_<<2;
    BP5(t15,t16,t17,t18,t19,m0,a0) BP5(t20,t21,t22,t23,t24,m0,a0)
    __builtin_amdgcn_sched_barrier(0);
    BP5(t15,t16,t17,t18,t19,m1,a1) BP5(t20,t21,t22,t23,t24,m1,a1)
    __builtin_amdgcn_sched_barrier(0);
    BP5(t15,t16,t17,t18,t19,m2,a2) BP5(t20,t21,t22,t23,t24,m2,a2)
    __builtin_amdgcn_sched_barrier(0);
    BP5(t15,t16,t17,t18,t19,m3,a3) BP5(t20,t21,t22,t23,t24,m3,a3)
    __builtin_amdgcn_sched_barrier(0);
    BP5(t15,t16,t17,t18,t19,m4,a4) BP5(t20,t21,t22,t23,t24,m4,a4)
    __builtin_amdgcn_sched_barrier(0);
  }
  // ---- panel 3: t15..t19, trail t20..t24 ----
  {
    float m0,m1,m2,m3,m4; int q0_,q1_,q2_,q3_,q4_;
    PSTEP3(t15, m0, q0_)
    RLU(t16,m0,q0_) RLU(t17,m0,q0_) RLU(t18,m0,q0_) RLU(t19,m0,q0_)
    PSTEP3(t16, m1, q1_)
    RLU(t17,m1,q1_) RLU(t18,m1,q1_) RLU(t19,m1,q1_)
    PSTEP3(t17, m2, q2_)
    RLU(t18,m2,q2_) RLU(t19,m2,q2_)
    PSTEP3(t18, m3, q3_)
    RLU(t19,m3,q3_)
    PSTEP3(t19, m4, q4_)
    const int a0=q0_<<2,a1=q1_<<2,a2=q2_<<2,a3=q3_<<2,a4=q4_<<2;
    BP5(t20,t21,t22,t23,t24,m0,a0)
    BP5(t20,t21,t22,t23,t24,m1,a1)
    BP5(t20,t21,t22,t23,t24,m2,a2)
    BP5(t20,t21,t22,t23,t24,m3,a3)
    BP5(t20,t21,t22,t23,t24,m4,a4)
    __builtin_amdgcn_sched_barrier(0);
  }
  // ---- panel 4: t20..t24, no trail ----
  {
    float m0,m1,m2,m3,m4; int q0_,q1_,q2_,q3_,q4_;
    PSTEP3(t20, m0, q0_)
    RLU(t21,m0,q0_) RLU(t22,m0,q0_) RLU(t23,m0,q0_) RLU(t24,m0,q0_)
    PSTEP3(t21, m1, q1_)
    RLU(t22,m1,q1_) RLU(t23,m1,q1_) RLU(t24,m1,q1_)
    PSTEP3(t22, m2, q2_)
    RLU(t23,m2,q2_) RLU(t24,m2,q2_)
    PSTEP3(t23, m3, q3_)
    RLU(t24,m3,q3_)
    PSTEP3(t24, m4, q4_)
    (void)m0;(void)m1;(void)m2;(void)m3;(void)m4;
  }

  const double logdet =
      log((double)mant_prod) + (double)esum * 0.6931471805599453;
  const int sgn = (((sgnx >> 31) + (unsigned)invsum) & 1u) ? -1 : 1;

  if (lane == 0) {
    detl[spin][kd][0] = logdet;
    detl[spin][kd][1] = (double)sgn;
  }
  __syncthreads();

  // ---- fused combine (identical op order to the old combine_kernel) ----
  if (tid == 0) {
    double t[KDET], s[KDET], m = -1e300;
    #pragma unroll
    for (int k2 = 0; k2 < KDET; ++k2) {
      t[k2] = detl[0][k2][0] + detl[1][k2][0];
      s[k2] = detl[0][k2][1] * detl[1][k2][1];
      if (t[k2] > m) m = t[k2];
    }
    double sum = 0.0;
    #pragma unroll
    for (int k2 = 0; k2 < KDET; ++k2) {
      if (t[k2] > -1e290) sum += s[k2] * exp(t[k2] - m);
    }
    double pw = (m > -1e290) ? exp(m) * fabs(sum) : 0.0;
    double la = log(pw + 1e-30);                 // reproduce ref clamp exactly
    out[b]     = (float)la;
    out[B + b] = (sum >= 0.0) ? 0.0f : 3.14159265358979f;
  }
}

extern "C" void kernel_launch(void* const* d_in, const int* in_sizes, int n_in,
                              void* d_out, int out_size, void* d_ws, size_t ws_size,
                              hipStream_t stream) {
  const int*   configs = (const int*)  d_in[0];
  const float* tok     = (const float*)d_in[1];
  const float* pos     = (const float*)d_in[2];
  const float* W       = (const float*)d_in[3];
  const float* bv      = (const float*)d_in[4];

  float*  wsf  = (float*)d_ws;
  float*  T    = wsf;                       // 4*400 floats
  float*  P    = wsf + 4 * NTAB;            // 144*400 floats
  const int B = in_sizes[0] / NSITE;

  tp_kernel<<<(148 * NTAB * 4 + 255) / 256, 256, 0, stream>>>(tok, pos, W, bv, T, P);
  det_kernel<<<B, 512, 0, stream>>>(configs, T, P, (float*)d_out, B);
}

// Round 13
// 195.504 us; speedup vs baseline: 1.3954x; 1.3954x over previous
//
#include <hip/hip_runtime.h>
#include <math.h>

#define NSITE 100
#define NOCC  50
#define DIM   128
#define KDET  4
#define NTAB  400                         // K*(N_UP+N_DOWN)

// ---------------------------------------------------------------------------
// R18: GEMM collapsed into T[4][400]/P'[144][400] table adds.
// R23: two-panel LU (25 live cols max): clean alloc, 181us @ VALUBusy 86%.
// R24/25: phase-2 broadcasts -> ds_bpermute (LDS pipe): 141.7us. Works:
//      independent per-column chains hide crossbar latency.
// R26/R27/R30: THREE attempts to push DS ops into the serial factor path
//      (full, hybrid, blocked-panel) all regressed hard (237/185/221us).
//      CLOSED: serial phases = 100% readlane, replay phase = 100% bpermute.
// R28: occupancy 60->72%: flat. R29: combine fused, tp split-K: total flat
//      at 195us -> ~54us non-det residue is fixed overhead.
// R31 (this round): REVERT to R29 (best: 195.2us, det 141.4) + one
//      zero-risk probe: split each step's update tail into {all readlanes
//      -> pcv[] temps} then {all fmas}. Breaks the v_readlane->SGPR->v_fma
//      forwarding hazard (1-op distance -> N-op distance). Bit-exact:
//      readlanes see pre-update values in both orders (pivot row never
//      modified within a step).
// ---------------------------------------------------------------------------

// Wave64 max-reduction via DPP (VALU-only). Lane 63 ends with global max.
__device__ __forceinline__ unsigned dpp_max64_to_lane63(unsigned x) {
  unsigned t;
  t = (unsigned)__builtin_amdgcn_update_dpp((int)x, (int)x, 0x111, 0xf, 0xf, false);
  x = x > t ? x : t;
  t = (unsigned)__builtin_amdgcn_update_dpp((int)x, (int)x, 0x112, 0xf, 0xf, false);
  x = x > t ? x : t;
  t = (unsigned)__builtin_amdgcn_update_dpp((int)x, (int)x, 0x114, 0xf, 0xf, false);
  x = x > t ? x : t;
  t = (unsigned)__builtin_amdgcn_update_dpp((int)x, (int)x, 0x118, 0xf, 0xf, false);
  x = x > t ? x : t;
  t = (unsigned)__builtin_amdgcn_update_dpp((int)x, (int)x, 0x142, 0xa, 0xf, false);
  x = x > t ? x : t;
  t = (unsigned)__builtin_amdgcn_update_dpp((int)x, (int)x, 0x143, 0xc, 0xf, false);
  x = x > t ? x : t;
  return x;
}

// 25-wide repeat
#define REPC(X) X(0) X(1) X(2) X(3) X(4) X(5) X(6) X(7) X(8) X(9) \
  X(10) X(11) X(12) X(13) X(14) X(15) X(16) X(17) X(18) X(19) \
  X(20) X(21) X(22) X(23) X(24)

// ---- Precompute: T[c][j] = tok[c].W_j ; P'[s][j] = pos[s].W_j + b_j ------
// Split-K x4: lanes (4q+h) handle quarter h of output q; shfl_xor combine.
__global__ __launch_bounds__(256) void tp_kernel(
    const float* __restrict__ tok, const float* __restrict__ pos,
    const float* __restrict__ W,   const float* __restrict__ bvec,
    float* __restrict__ T, float* __restrict__ P)
{
  const int gid = blockIdx.x * 256 + threadIdx.x;
  if (gid >= 148 * NTAB * 4) return;
  const int q   = gid >> 2;
  const int h   = gid & 3;
  const int row = q / NTAB;
  const int col = q - row * NTAB;
  const float4* h4 = (const float4*)((row < 4) ? (tok + (size_t)row * DIM)
                                               : (pos + (size_t)(row - 4) * DIM));
  const float4* w4 = (const float4*)(W + (size_t)col * DIM);
  float acc = 0.0f;
  #pragma unroll
  for (int i = 0; i < 8; ++i) {
    float4 a = h4[h * 8 + i], b = w4[h * 8 + i];
    acc = fmaf(a.x, b.x, acc);
    acc = fmaf(a.y, b.y, acc);
    acc = fmaf(a.z, b.z, acc);
    acc = fmaf(a.w, b.w, acc);
  }
  acc += __shfl_xor(acc, 1);
  acc += __shfl_xor(acc, 2);
  if (h == 0) {
    if (row < 4) T[(size_t)row * NTAB + col] = acc;
    else         P[(size_t)(row - 4) * NTAB + col] = acc + bvec[col];
  }
}

// One block per batch. 8 waves: wave w -> spin = w>>2, det k = w&3.
// Lane r owns row r of phi. Two-panel LU per wave; combine fused at end.
__global__ __launch_bounds__(512)
__attribute__((amdgpu_waves_per_eu(8)))
void det_kernel(
    const int*   __restrict__ configs,   // (B,100) int32
    const float* __restrict__ T,         // (4,400)
    const float* __restrict__ P,         // (144,400)  includes bias
    float*       __restrict__ out,       // planar complex64
    int B)
{
  const int b = blockIdx.x;

  __shared__ float stash[8][25][50];       // 40000B multiplier stash
  __shared__ int cfg[NSITE];               // 400B
  __shared__ int idxs[2][NOCC];            // 400B
  __shared__ unsigned long long omask[2][2];  // 32B
  __shared__ double detl[2][KDET][2];      // 128B  -> total 40960B exactly

  const int tid = threadIdx.x;

  // ---- wave-parallel occupied-index build for BOTH spins ----
  int  cval = 0;
  bool ou = false, od = false;
  if (tid < NSITE) {
    cval = configs[(size_t)b * NSITE + tid];
    cfg[tid] = cval;
    ou = (cval == 1) || (cval == 3);
    od = (cval == 2) || (cval == 3);
  }
  const unsigned long long balu = __ballot(ou);
  const unsigned long long bald = __ballot(od);
  if ((tid & 63) == 0 && tid < 128) {
    omask[0][tid >> 6] = balu;
    omask[1][tid >> 6] = bald;
  }
  __syncthreads();
  if (tid < NSITE) {
    #pragma unroll
    for (int s = 0; s < 2; ++s) {
      const unsigned long long m0 = omask[s][0], m1 = omask[s][1];
      const bool occv = (s == 0) ? ou : od;
      const int mtot = __popcll(m0) + __popcll(m1);
      const int need = (mtot < NOCC) ? (NOCC - mtot) : 0;
      int pocc;
      if (tid >= 64) pocc = __popcll(m0) + __popcll(m1 & ((1ull << (tid - 64)) - 1ull));
      else           pocc = __popcll(m0 & ((1ull << tid) - 1ull));
      const int punocc = tid - pocc;
      const bool sel = occv ? (pocc < NOCC) : (punocc < need);
      const int  poscap = (pocc  < NOCC) ? pocc  : NOCC;
      const int  pfill  = (punocc < need) ? punocc : need;
      if (sel) idxs[s][poscap + pfill] = tid;
    }
  }
  __syncthreads();

  const int lane   = tid & 63;
  const int wave   = tid >> 6;
  const int wave_u = __builtin_amdgcn_readfirstlane(wave);
  const int spin   = wave_u >> 2;
  const int kd     = wave_u & 3;
  const int colbase = spin * 200 + kd * 50;              // uniform

  const bool act  = (lane < NOCC);
  const int  site = idxs[spin][act ? lane : 0];
  const int  cc0  = cfg[site];
  const float* Trow = T + (size_t)cc0  * NTAB + colbase;
  const float* Prow = P + (size_t)site * NTAB + colbase;
  // colbase multiple of 50 -> byte offset multiple of 200 -> 8-aligned
  const float2* T2 = (const float2*)Trow;
  const float2* P2 = (const float2*)Prow;

  // ================= phase 1: cols 0..24 in c0..c24 =================
  #define DECLC(i) float c##i;
  REPC(DECLC)
  #undef DECLC
  #define LQ(i0, i1) { float2 a = T2[(i0) / 2], d = P2[(i0) / 2]; \
      c##i0 = a.x + d.x; c##i1 = a.y + d.y; }
  LQ(0, 1)  LQ(2, 3)  LQ(4, 5)  LQ(6, 7)  LQ(8, 9)  LQ(10, 11)
  LQ(12, 13) LQ(14, 15) LQ(16, 17) LQ(18, 19) LQ(20, 21) LQ(22, 23)
  #undef LQ
  c24 = Trow[24] + Prow[24];
  #define ZC(i) c##i = act ? c##i : 0.0f;
  REPC(ZC)
  #undef ZC

  unsigned aliveq = act ? 0xFFFFFFFFu : 0u;   // per-lane alive mask
  float    mant_prod = 1.0f;                  // pivot mantissa product < 2^50
  int      esum = 0;
  unsigned sgnx = 0u;
  unsigned long long chosen = 0ull;
  int      invsum = 0;
  const unsigned lu = (unsigned)lane;
  unsigned long long pp[3] = {0ull, 0ull, 0ull};  // packed pivot lanes, 6b ea
  float pcv[25];   // constant-indexed pivot-row temps (stay in registers)

  // ---- split update chains, c family: ALL readlanes, then ALL fmas ----
  #define RLC(L) pcv[L] = __int_as_float( \
      __builtin_amdgcn_readlane(__float_as_int(c##L), p));
  #define FMC(L) c##L = fmaf(-mult, pcv[L], c##L);
  #define RCF_25
  #define RCF_24 RLC(24)
  #define RCF_23 RLC(23) RCF_24
  #define RCF_22 RLC(22) RCF_23
  #define RCF_21 RLC(21) RCF_22
  #define RCF_20 RLC(20) RCF_21
  #define RCF_19 RLC(19) RCF_20
  #define RCF_18 RLC(18) RCF_19
  #define RCF_17 RLC(17) RCF_18
  #define RCF_16 RLC(16) RCF_17
  #define RCF_15 RLC(15) RCF_16
  #define RCF_14 RLC(14) RCF_15
  #define RCF_13 RLC(13) RCF_14
  #define RCF_12 RLC(12) RCF_13
  #define RCF_11 RLC(11) RCF_12
  #define RCF_10 RLC(10) RCF_11
  #define RCF_9  RLC(9)  RCF_10
  #define RCF_8  RLC(8)  RCF_9
  #define RCF_7  RLC(7)  RCF_8
  #define RCF_6  RLC(6)  RCF_7
  #define RCF_5  RLC(5)  RCF_6
  #define RCF_4  RLC(4)  RCF_5
  #define RCF_3  RLC(3)  RCF_4
  #define RCF_2  RLC(2)  RCF_3
  #define RCF_1  RLC(1)  RCF_2
  #define FCF_25
  #define FCF_24 FMC(24)
  #define FCF_23 FMC(23) FCF_24
  #define FCF_22 FMC(22) FCF_23
  #define FCF_21 FMC(21) FCF_22
  #define FCF_20 FMC(20) FCF_21
  #define FCF_19 FMC(19) FCF_20
  #define FCF_18 FMC(18) FCF_19
  #define FCF_17 FMC(17) FCF_18
  #define FCF_16 FMC(16) FCF_17
  #define FCF_15 FMC(15) FCF_16
  #define FCF_14 FMC(14) FCF_15
  #define FCF_13 FMC(13) FCF_14
  #define FCF_12 FMC(12) FCF_13
  #define FCF_11 FMC(11) FCF_12
  #define FCF_10 FMC(10) FCF_11
  #define FCF_9  FMC(9)  FCF_10
  #define FCF_8  FMC(8)  FCF_9
  #define FCF_7  FMC(7)  FCF_8
  #define FCF_6  FMC(6)  FCF_7
  #define FCF_5  FMC(5)  FCF_6
  #define FCF_4  FMC(4)  FCF_5
  #define FCF_3  FMC(3)  FCF_4
  #define FCF_2  FMC(2)  FCF_3
  #define FCF_1  FMC(1)  FCF_2
  #define UCF_25
  #define UCF_24 RCF_24 FCF_24
  #define UCF_23 RCF_23 FCF_23
  #define UCF_22 RCF_22 FCF_22
  #define UCF_21 RCF_21 FCF_21
  #define UCF_20 RCF_20 FCF_20
  #define UCF_19 RCF_19 FCF_19
  #define UCF_18 RCF_18 FCF_18
  #define UCF_17 RCF_17 FCF_17
  #define UCF_16 RCF_16 FCF_16
  #define UCF_15 RCF_15 FCF_15
  #define UCF_14 RCF_14 FCF_14
  #define UCF_13 RCF_13 FCF_13
  #define UCF_12 RCF_12 FCF_12
  #define UCF_11 RCF_11 FCF_11
  #define UCF_10 RCF_10 FCF_10
  #define UCF_9  RCF_9  FCF_9
  #define UCF_8  RCF_8  FCF_8
  #define UCF_7  RCF_7  FCF_7
  #define UCF_6  RCF_6  FCF_6
  #define UCF_5  RCF_5  FCF_5
  #define UCF_4  RCF_4  FCF_4
  #define UCF_3  RCF_3  FCF_3
  #define UCF_2  RCF_2  FCF_2
  #define UCF_1  RCF_1  FCF_1

  // Step J (global step J, 0..24): pivot, account, stash mult, update tail.
  #define P1STEP(J, N) { \
    unsigned key = ((__float_as_uint(c##J) & 0x7FFFFFC0u) | lu) & aliveq; \
    key = dpp_max64_to_lane63(key); \
    const int p = __builtin_amdgcn_readlane((int)key, 63) & 63; \
    const unsigned pb = (unsigned)__builtin_amdgcn_readlane( \
        __float_as_int(c##J), p); \
    esum += (int)((pb >> 23) & 0xFFu) - 127; \
    sgnx ^= (pb & 0x80000000u); \
    mant_prod *= __uint_as_float((pb & 0x007FFFFFu) | 0x3F800000u); \
    invsum += __popcll(chosen >> (p + 1)); \
    chosen |= 1ull << (unsigned)p; \
    aliveq = (lane == p) ? 0u : aliveq; \
    pp[(J) / 10] |= ((unsigned long long)(unsigned)p) << (6 * ((J) % 10)); \
    const float piv = __uint_as_float(pb); \
    float r0 = __builtin_amdgcn_rcpf(piv); \
    r0 = fmaf(fmaf(-piv, r0, 1.0f), r0, r0); \
    const float rp = ((pb & 0x7FFFFFFFu) != 0u) ? r0 : 0.0f; \
    const float mult = __uint_as_float(__float_as_uint(c##J * rp) & aliveq); \
    if (act) stash[wave_u][(J)][lane] = mult; \
    UCF_##N \
  }

  P1STEP(0,1)   P1STEP(1,2)   P1STEP(2,3)   P1STEP(3,4)   P1STEP(4,5)
  P1STEP(5,6)   P1STEP(6,7)   P1STEP(7,8)   P1STEP(8,9)   P1STEP(9,10)
  P1STEP(10,11) P1STEP(11,12) P1STEP(12,13) P1STEP(13,14) P1STEP(14,15)
  P1STEP(15,16) P1STEP(16,17) P1STEP(17,18) P1STEP(18,19) P1STEP(19,20)
  P1STEP(20,21) P1STEP(21,22) P1STEP(22,23) P1STEP(23,24) P1STEP(24,25)
  #undef P1STEP

  // ================= phase 2: cols 25..49, replay steps 0..24 ============
  // Broadcasts ride the LDS pipe (ds_bpermute). Bit-exact vs readlane.
  #define DECLT(i) float t##i;
  REPC(DECLT)
  #undef DECLT
  #define LT(i) t##i = Trow[25 + (i)] + Prow[25 + (i)];
  REPC(LT)
  #undef LT
  #define ZT(i) t##i = act ? t##i : 0.0f;
  REPC(ZT)
  #undef ZT

  // bpermute update: pc pulled from lane (pa>>2) through LDS crossbar
  #define BT(L) { const float pc = __int_as_float( \
      __builtin_amdgcn_ds_bpermute(pa, __float_as_int(t##L))); \
      t##L = fmaf(-mult, pc, t##L); }

  #define P2J(J) { \
    const int pa = ((int)((pp[(J) / 10] >> (6 * ((J) % 10))) & 63ull)) << 2; \
    const float mult = stash[wave_u][(J)][lane < NOCC ? lane : 0]; \
    BT(0)  BT(1)  BT(2)  BT(3)  BT(4)  BT(5) \
    __builtin_amdgcn_sched_barrier(0); \
    BT(6)  BT(7)  BT(8)  BT(9)  BT(10) BT(11) \
    __builtin_amdgcn_sched_barrier(0); \
    BT(12) BT(13) BT(14) BT(15) BT(16) BT(17) \
    __builtin_amdgcn_sched_barrier(0); \
    BT(18) BT(19) BT(20) BT(21) BT(22) BT(23) BT(24) \
    __builtin_amdgcn_sched_barrier(0); \
  }
  P2J(0)  P2J(1)  P2J(2)  P2J(3)  P2J(4)  P2J(5)  P2J(6)  P2J(7)
  P2J(8)  P2J(9)  P2J(10) P2J(11) P2J(12) P2J(13) P2J(14) P2J(15)
  P2J(16) P2J(17) P2J(18) P2J(19) P2J(20) P2J(21) P2J(22) P2J(23)
  P2J(24)
  #undef P2J
  #undef BT

  // ================= phase 3: factor steps 25..49 on t0..t24 =============
  #define RLT(L) pcv[L] = __int_as_float( \
      __builtin_amdgcn_readlane(__float_as_int(t##L), p));
  #define FMT(L) t##L = fmaf(-mult, pcv[L], t##L);
  #define RTF_25
  #define RTF_24 RLT(24)
  #define RTF_23 RLT(23) RTF_24
  #define RTF_22 RLT(22) RTF_23
  #define RTF_21 RLT(21) RTF_22
  #define RTF_20 RLT(20) RTF_21
  #define RTF_19 RLT(19) RTF_20
  #define RTF_18 RLT(18) RTF_19
  #define RTF_17 RLT(17) RTF_18
  #define RTF_16 RLT(16) RTF_17
  #define RTF_15 RLT(15) RTF_16
  #define RTF_14 RLT(14) RTF_15
  #define RTF_13 RLT(13) RTF_14
  #define RTF_12 RLT(12) RTF_13
  #define RTF_11 RLT(11) RTF_12
  #define RTF_10 RLT(10) RTF_11
  #define RTF_9  RLT(9)  RTF_10
  #define RTF_8  RLT(8)  RTF_9
  #define RTF_7  RLT(7)  RTF_8
  #define RTF_6  RLT(6)  RTF_7
  #define RTF_5  RLT(5)  RTF_6
  #define RTF_4  RLT(4)  RTF_5
  #define RTF_3  RLT(3)  RTF_4
  #define RTF_2  RLT(2)  RTF_3
  #define RTF_1  RLT(1)  RTF_2
  #define FTF_25
  #define FTF_24 FMT(24)
  #define FTF_23 FMT(23) FTF_24
  #define FTF_22 FMT(22) FTF_23
  #define FTF_21 FMT(21) FTF_22
  #define FTF_20 FMT(20) FTF_21
  #define FTF_19 FMT(19) FTF_20
  #define FTF_18 FMT(18) FTF_19
  #define FTF_17 FMT(17) FTF_18
  #define FTF_16 FMT(16) FTF_17
  #define FTF_15 FMT(15) FTF_16
  #define FTF_14 FMT(14) FTF_15
  #define FTF_13 FMT(13) FTF_14
  #define FTF_12 FMT(12) FTF_13
  #define FTF_11 FMT(11) FTF_12
  #define FTF_10 FMT(10) FTF_11
  #define FTF_9  FMT(9)  FTF_10
  #define FTF_8  FMT(8)  FTF_9
  #define FTF_7  FMT(7)  FTF_8
  #define FTF_6  FMT(6)  FTF_7
  #define FTF_5  FMT(5)  FTF_6
  #define FTF_4  FMT(4)  FTF_5
  #define FTF_3  FMT(3)  FTF_4
  #define FTF_2  FMT(2)  FTF_3
  #define FTF_1  FMT(1)  FTF_2
  #define UTF_25
  #define UTF_24 RTF_24 FTF_24
  #define UTF_23 RTF_23 FTF_23
  #define UTF_22 RTF_22 FTF_22
  #define UTF_21 RTF_21 FTF_21
  #define UTF_20 RTF_20 FTF_20
  #define UTF_19 RTF_19 FTF_19
  #define UTF_18 RTF_18 FTF_18
  #define UTF_17 RTF_17 FTF_17
  #define UTF_16 RTF_16 FTF_16
  #define UTF_15 RTF_15 FTF_15
  #define UTF_14 RTF_14 FTF_14
  #define UTF_13 RTF_13 FTF_13
  #define UTF_12 RTF_12 FTF_12
  #define UTF_11 RTF_11 FTF_11
  #define UTF_10 RTF_10 FTF_10
  #define UTF_9  RTF_9  FTF_9
  #define UTF_8  RTF_8  FTF_8
  #define UTF_7  RTF_7  FTF_7
  #define UTF_6  RTF_6  FTF_6
  #define UTF_5  RTF_5  FTF_5
  #define UTF_4  RTF_4  FTF_4
  #define UTF_3  RTF_3  FTF_3
  #define UTF_2  RTF_2  FTF_2
  #define UTF_1  RTF_1  FTF_1

  #define P3STEP(L, N) { \
    unsigned key = ((__float_as_uint(t##L) & 0x7FFFFFC0u) | lu) & aliveq; \
    key = dpp_max64_to_lane63(key); \
    const int p = __builtin_amdgcn_readlane((int)key, 63) & 63; \
    const unsigned pb = (unsigned)__builtin_amdgcn_readlane( \
        __float_as_int(t##L), p); \
    esum += (int)((pb >> 23) & 0xFFu) - 127; \
    sgnx ^= (pb & 0x80000000u); \
    mant_prod *= __uint_as_float((pb & 0x007FFFFFu) | 0x3F800000u); \
    invsum += __popcll(chosen >> (p + 1)); \
    chosen |= 1ull << (unsigned)p; \
    aliveq = (lane == p) ? 0u : aliveq; \
    const float piv = __uint_as_float(pb); \
    float r0 = __builtin_amdgcn_rcpf(piv); \
    r0 = fmaf(fmaf(-piv, r0, 1.0f), r0, r0); \
    const float rp = ((pb & 0x7FFFFFFFu) != 0u) ? r0 : 0.0f; \
    const float mult = __uint_as_float(__float_as_uint(t##L * rp) & aliveq); \
    UTF_##N \
  }

  P3STEP(0,1)   P3STEP(1,2)   P3STEP(2,3)   P3STEP(3,4)   P3STEP(4,5)
  P3STEP(5,6)   P3STEP(6,7)   P3STEP(7,8)   P3STEP(8,9)   P3STEP(9,10)
  P3STEP(10,11) P3STEP(11,12) P3STEP(12,13) P3STEP(13,14) P3STEP(14,15)
  P3STEP(15,16) P3STEP(16,17) P3STEP(17,18) P3STEP(18,19) P3STEP(19,20)
  P3STEP(20,21) P3STEP(21,22) P3STEP(22,23) P3STEP(23,24) P3STEP(24,25)
  #undef P3STEP

  const double logdet =
      log((double)mant_prod) + (double)esum * 0.6931471805599453;
  const int sgn = (((sgnx >> 31) + (unsigned)invsum) & 1u) ? -1 : 1;

  if (lane == 0) {
    detl[spin][kd][0] = logdet;
    detl[spin][kd][1] = (double)sgn;
  }
  __syncthreads();

  // ---- fused combine (identical op order to the old combine_kernel) ----
  if (tid == 0) {
    double t[KDET], s[KDET], m = -1e300;
    #pragma unroll
    for (int k2 = 0; k2 < KDET; ++k2) {
      t[k2] = detl[0][k2][0] + detl[1][k2][0];
      s[k2] = detl[0][k2][1] * detl[1][k2][1];
      if (t[k2] > m) m = t[k2];
    }
    double sum = 0.0;
    #pragma unroll
    for (int k2 = 0; k2 < KDET; ++k2) {
      if (t[k2] > -1e290) sum += s[k2] * exp(t[k2] - m);
    }
    double pw = (m > -1e290) ? exp(m) * fabs(sum) : 0.0;
    double la = log(pw + 1e-30);                 // reproduce ref clamp exactly
    out[b]     = (float)la;
    out[B + b] = (sum >= 0.0) ? 0.0f : 3.14159265358979f;
  }
}

extern "C" void kernel_launch(void* const* d_in, const int* in_sizes, int n_in,
                              void* d_out, int out_size, void* d_ws, size_t ws_size,
                              hipStream_t stream) {
  const int*   configs = (const int*)  d_in[0];
  const float* tok     = (const float*)d_in[1];
  const float* pos     = (const float*)d_in[2];
  const float* W       = (const float*)d_in[3];
  const float* bv      = (const float*)d_in[4];

  float*  wsf  = (float*)d_ws;
  float*  T    = wsf;                       // 4*400 floats
  float*  P    = wsf + 4 * NTAB;            // 144*400 floats
  const int B = in_sizes[0] / NSITE;

  tp_kernel<<<(148 * NTAB * 4 + 255) / 256, 256, 0, stream>>>(tok, pos, W, bv, T, P);
  det_kernel<<<B, 512, 0, stream>>>(configs, T, P, (float*)d_out, B);
}